// Round 5
// baseline (1304.472 us; speedup 1.0000x reference)
//
#include <hip/hip_runtime.h>
#include <hip/hip_fp16.h>

#define HID 128
#define INF 500
#define NCLS 16
#define PW  112    // projected width: [s0 | p1 q3a q4a | p2 q3b q4b]
#define NBKMAX 1024

typedef __attribute__((ext_vector_type(8))) short short8v;
typedef __attribute__((ext_vector_type(4))) float f32x4;

// split fp32 into hi (truncated bf16) + lo (bf16 of remainder)
__device__ __forceinline__ void split_bf16(float v, unsigned short& h, unsigned short& l) {
  unsigned u = __float_as_uint(v);
  h = (unsigned short)(u >> 16);
  float hf = __uint_as_float(u & 0xFFFF0000u);
  l = (unsigned short)(__float_as_uint(v - hf) >> 16);
}

__device__ __forceinline__ void cvt8(float4 c0, float4 c1, short8v& h8, short8v& l8) {
  float va[8] = {c0.x, c0.y, c0.z, c0.w, c1.x, c1.y, c1.z, c1.w};
#pragma unroll
  for (int j = 0; j < 8; ++j) {
    unsigned short h, l;
    split_bf16(va[j], h, l);
    h8[j] = (short)h;
    l8[j] = (short)l;
  }
}

// ---------------- weight prep (fused): fragment-linear hi/lo bf16 planes ----------------
// B-frag for mfma_f32_16x16x32_bf16: lane holds B[k'=(lane>>4)*8+j][n=lane&15]
// we_frag: [16 kstep][8 nf][64 lane][8 j]; wc_frag: [4 kstep][7 nf][64 lane][8 j]
// wc col-blocks permuted [0,1,3,5,2,4,6]
__global__ __launch_bounds__(256) void prep_w(
    const float* __restrict__ we, const float* __restrict__ wc,
    unsigned short* __restrict__ wh, unsigned short* __restrict__ wl,
    unsigned short* __restrict__ ch, unsigned short* __restrict__ cl) {
  const int bid = blockIdx.x;
  if (bid < 256) {
    int idx = bid * 256 + threadIdx.x;     // < 512*128
    int k = idx >> 7, nn = idx & 127;
    float v = (k < INF) ? we[k * HID + nn] : 0.f;
    unsigned short h, l;
    split_bf16(v, h, l);
    int kstep = k >> 5, ks = k & 31;
    int lane = (nn & 15) | ((ks >> 3) << 4);
    int j = ks & 7, nf = nn >> 4;
    size_t o = (((size_t)(kstep * 8 + nf)) * 64 + lane) * 8 + j;
    wh[o] = h;
    wl[o] = l;
  } else {
    int idx = (bid - 256) * 256 + threadIdx.x;
    if (idx >= HID * PW) return;
    int k = idx / PW, np = idx % PW;
    int o = np >> 4;
    int blk = (o == 0) ? 0 : ((o < 4) ? (2 * o - 1) : (2 * o - 6));
    float v = wc[(blk * HID + k) * NCLS + (np & 15)];
    unsigned short h, l;
    split_bf16(v, h, l);
    int kstep = k >> 5, ks = k & 31;
    int lane = (np & 15) | ((ks >> 3) << 4);
    int j = ks & 7, nf = np >> 4;
    size_t of = (((size_t)(kstep * 7 + nf)) * 64 + lane) * 8 + j;
    ch[of] = h;
    cl[of] = l;
  }
}

// ---------------- embed MFMA: r0 = relu(x @ we), bf16x3, no LDS ----------------
__global__ __launch_bounds__(128) void embed_mfma(
    const float* __restrict__ x, const unsigned short* __restrict__ wh,
    const unsigned short* __restrict__ wl, unsigned short* __restrict__ r0h,
    unsigned short* __restrict__ r0l, int n) {
  const int wave = threadIdx.x >> 6, lane = threadIdx.x & 63;
  const int row0 = blockIdx.x * 64 + wave * 32;
  const int rA = lane & 15, kg = lane >> 4;

  f32x4 acc[2][8];
#pragma unroll
  for (int rf = 0; rf < 2; ++rf)
#pragma unroll
    for (int nf = 0; nf < 8; ++nf)
#pragma unroll
      for (int r = 0; r < 4; ++r) acc[rf][nf][r] = 0.f;

  const float* xr0 = &x[(size_t)min(row0 + rA, n - 1) * INF];
  const float* xr1 = &x[(size_t)min(row0 + 16 + rA, n - 1) * INF];

  for (int kstep = 0; kstep < 16; ++kstep) {
    const int kb = kstep * 32 + kg * 8;
    const bool v0 = (kb + 4 <= INF), v1 = (kb + 8 <= INF);
    const int ka0 = v0 ? kb : 0, ka1 = v1 ? kb + 4 : 0;
    float4 z4 = make_float4(0.f, 0.f, 0.f, 0.f);
    float4 a0c0 = *(const float4*)&xr0[ka0]; if (!v0) a0c0 = z4;
    float4 a0c1 = *(const float4*)&xr0[ka1]; if (!v1) a0c1 = z4;
    float4 a1c0 = *(const float4*)&xr1[ka0]; if (!v0) a1c0 = z4;
    float4 a1c1 = *(const float4*)&xr1[ka1]; if (!v1) a1c1 = z4;

    short8v ah[2], al[2];
    cvt8(a0c0, a0c1, ah[0], al[0]);
    cvt8(a1c0, a1c1, ah[1], al[1]);

    const size_t bbase = ((size_t)kstep * 8 * 64 + lane) * 8;
    short8v Bh[8], Bl[8];
#pragma unroll
    for (int nf = 0; nf < 8; ++nf) {
      Bh[nf] = *(const short8v*)&wh[bbase + (size_t)nf * 512];
      Bl[nf] = *(const short8v*)&wl[bbase + (size_t)nf * 512];
    }
#pragma unroll
    for (int rf = 0; rf < 2; ++rf)
#pragma unroll
      for (int nf = 0; nf < 8; ++nf) {
        acc[rf][nf] = __builtin_amdgcn_mfma_f32_16x16x32_bf16(ah[rf], Bh[nf], acc[rf][nf], 0, 0, 0);
        acc[rf][nf] = __builtin_amdgcn_mfma_f32_16x16x32_bf16(ah[rf], Bl[nf], acc[rf][nf], 0, 0, 0);
        acc[rf][nf] = __builtin_amdgcn_mfma_f32_16x16x32_bf16(al[rf], Bh[nf], acc[rf][nf], 0, 0, 0);
      }
  }

#pragma unroll
  for (int rf = 0; rf < 2; ++rf)
#pragma unroll
    for (int nf = 0; nf < 8; ++nf) {
      const int row = row0 + rf * 16 + kg * 4;
      const int col = nf * 16 + rA;
#pragma unroll
      for (int r = 0; r < 4; ++r) {
        if (row + r < n) {
          float v = fmaxf(acc[rf][nf][r], 0.f);
          unsigned short h, l;
          split_bf16(v, h, l);
          r0h[(size_t)(row + r) * HID + col] = h;
          r0l[(size_t)(row + r) * HID + col] = l;
        }
      }
    }
}

// ---------------- proj MFMA: [s0|Pa1|Pa2] = r0 @ wcP, bf16x3, K=128 ----------------
// nf 0 -> s0f fp32 [n][16]; nf 1..3 -> Pa1h fp16 [n][48]; nf 4..6 -> Pa2h fp16 [n][48]
__global__ __launch_bounds__(128) void proj_mfma(
    const unsigned short* __restrict__ r0h, const unsigned short* __restrict__ r0l,
    const unsigned short* __restrict__ ch, const unsigned short* __restrict__ cl,
    float* __restrict__ s0f, __half* __restrict__ Pa1h, __half* __restrict__ Pa2h, int n) {
  const int wave = threadIdx.x >> 6, lane = threadIdx.x & 63;
  const int row0 = blockIdx.x * 64 + wave * 32;
  const int rA = lane & 15, kg = lane >> 4;

  f32x4 acc[2][7];
#pragma unroll
  for (int rf = 0; rf < 2; ++rf)
#pragma unroll
    for (int nf = 0; nf < 7; ++nf)
#pragma unroll
      for (int r = 0; r < 4; ++r) acc[rf][nf][r] = 0.f;

  const unsigned short* a0h = &r0h[(size_t)min(row0 + rA, n - 1) * HID];
  const unsigned short* a0l = &r0l[(size_t)min(row0 + rA, n - 1) * HID];
  const unsigned short* a1h = &r0h[(size_t)min(row0 + 16 + rA, n - 1) * HID];
  const unsigned short* a1l = &r0l[(size_t)min(row0 + 16 + rA, n - 1) * HID];

#pragma unroll
  for (int kstep = 0; kstep < 4; ++kstep) {
    const int kb = kstep * 32 + kg * 8;
    short8v ah[2], al[2];
    ah[0] = *(const short8v*)&a0h[kb];
    al[0] = *(const short8v*)&a0l[kb];
    ah[1] = *(const short8v*)&a1h[kb];
    al[1] = *(const short8v*)&a1l[kb];

    const size_t bbase = ((size_t)kstep * 7 * 64 + lane) * 8;
    short8v Bh[7], Bl[7];
#pragma unroll
    for (int nf = 0; nf < 7; ++nf) {
      Bh[nf] = *(const short8v*)&ch[bbase + (size_t)nf * 512];
      Bl[nf] = *(const short8v*)&cl[bbase + (size_t)nf * 512];
    }
#pragma unroll
    for (int rf = 0; rf < 2; ++rf)
#pragma unroll
      for (int nf = 0; nf < 7; ++nf) {
        acc[rf][nf] = __builtin_amdgcn_mfma_f32_16x16x32_bf16(ah[rf], Bh[nf], acc[rf][nf], 0, 0, 0);
        acc[rf][nf] = __builtin_amdgcn_mfma_f32_16x16x32_bf16(ah[rf], Bl[nf], acc[rf][nf], 0, 0, 0);
        acc[rf][nf] = __builtin_amdgcn_mfma_f32_16x16x32_bf16(al[rf], Bh[nf], acc[rf][nf], 0, 0, 0);
      }
  }

#pragma unroll
  for (int rf = 0; rf < 2; ++rf)
#pragma unroll
    for (int nf = 0; nf < 7; ++nf) {
      const int row = row0 + rf * 16 + kg * 4;
#pragma unroll
      for (int r = 0; r < 4; ++r) {
        if (row + r < n) {
          float v = acc[rf][nf][r];
          if (nf == 0) s0f[(size_t)(row + r) * 16 + rA] = v;
          else if (nf < 4) Pa1h[(size_t)(row + r) * 48 + (nf - 1) * 16 + rA] = __float2half(v);
          else Pa2h[(size_t)(row + r) * 48 + (nf - 4) * 16 + rA] = __float2half(v);
        }
      }
    }
}

// ---------------- bucket CSR build (64 rows per bucket) ----------------
__global__ __launch_bounds__(256) void hist_buckets(
    const int* __restrict__ r1, int e1, const int* __restrict__ r2, int e2,
    int* __restrict__ bcnt1, int* __restrict__ bcnt2, int nbk) {
  __shared__ int h1[NBKMAX], h2[NBKMAX];
  for (int i = threadIdx.x; i < NBKMAX; i += 256) { h1[i] = 0; h2[i] = 0; }
  __syncthreads();
  const int total = e1 + e2;
  for (int i = blockIdx.x * 256 + threadIdx.x; i < total; i += gridDim.x * 256) {
    if (i < e1) atomicAdd(&h1[r1[i] >> 6], 1);
    else atomicAdd(&h2[r2[i - e1] >> 6], 1);
  }
  __syncthreads();
  for (int i = threadIdx.x; i < nbk; i += 256) {
    if (h1[i]) atomicAdd(&bcnt1[i], h1[i]);
    if (h2[i]) atomicAdd(&bcnt2[i], h2[i]);
  }
}

// scan bucket counts -> brp (bucket row ptr) + padded tails (stride 16 ints = 64B)
__global__ __launch_bounds__(256) void scan_buckets(
    const int* __restrict__ bcnt1, int* __restrict__ brp1, int* __restrict__ btail1,
    const int* __restrict__ bcnt2, int* __restrict__ brp2, int* __restrict__ btail2,
    int nbk) {
  const int* bc = blockIdx.x ? bcnt2 : bcnt1;
  int* rp = blockIdx.x ? brp2 : brp1;
  int* bt = blockIdx.x ? btail2 : btail1;
  __shared__ int sh[256];
  const int t = threadIdx.x;
  const int chunk = (nbk + 255) >> 8;
  const int lo = t * chunk;
  const int hi = min(lo + chunk, nbk);
  int s = 0;
  for (int i = lo; i < hi; ++i) s += bc[i];
  sh[t] = s;
  __syncthreads();
  for (int d = 1; d < 256; d <<= 1) {
    int v = (t >= d) ? sh[t - d] : 0;
    __syncthreads();
    sh[t] += v;
    __syncthreads();
  }
  int run = sh[t] - s;
  for (int i = lo; i < hi; ++i) { rp[i] = run; bt[i * 16] = run; run += bc[i]; }
  if (t == 255) rp[nbk] = sh[255];
}

// scatter edges into bucket-grouped pack; .x = col | (row%64)<<16  (requires n <= 65536)
__global__ void scatter_edges(
    const int* __restrict__ r1, const int* __restrict__ c1, const float* __restrict__ v1, int e1,
    const int* __restrict__ r2, const int* __restrict__ c2, const float* __restrict__ v2, int e2,
    int* __restrict__ btail1, int2* __restrict__ pack1,
    int* __restrict__ btail2, int2* __restrict__ pack2) {
  int i = blockIdx.x * blockDim.x + threadIdx.x;
  if (i < e1) {
    int r = r1[i];
    int pos = atomicAdd(&btail1[(r >> 6) << 4], 1);
    pack1[pos] = make_int2(c1[i] | ((r & 63) << 16), __float_as_int(v1[i]));
  } else if (i < e1 + e2) {
    int k = i - e1;
    int r = r2[k];
    int pos = atomicAdd(&btail2[(r >> 6) << 4], 1);
    pack2[pos] = make_int2(c2[k] | ((r & 63) << 16), __float_as_int(v2[k]));
  }
}

// ---------------- fused bucket SpMM (48-wide, both matrices) + combine ----------------
// acc1 = A1 @ [p1 q3a q4a], acc2 = A2 @ [p2 q3b q4b];
// wsum = s0 + acc1[:,0:16] + acc2[:,0:16]; m34 = [acc1[:,16:32]+acc2[:,16:32] | acc1[:,32:48]+acc2[:,32:48]]
__global__ __launch_bounds__(256) void spmm_bucket48(
    const int2* __restrict__ pack1, const int* __restrict__ brp1,
    const int2* __restrict__ pack2, const int* __restrict__ brp2,
    const __half* __restrict__ Pa1, const __half* __restrict__ Pa2,
    const float* __restrict__ s0f, float* __restrict__ wsum,
    float* __restrict__ m34, int n) {
  __shared__ float acc1[64][49];
  __shared__ float acc2[64][49];
  const int b = blockIdx.x, tid = threadIdx.x;
  for (int i = tid; i < 64 * 49; i += 256) { (&acc1[0][0])[i] = 0.f; (&acc2[0][0])[i] = 0.f; }
  __syncthreads();
  const int g = tid >> 4, c = tid & 15;
  int j1 = brp1[b + 1];
  for (int j = brp1[b] + g; j < j1; j += 16) {
    int2 cv = pack1[j];
    int col = cv.x & 0xFFFF, r6 = (cv.x >> 16) & 63;
    float v = __int_as_float(cv.y);
    const __half* src = &Pa1[(size_t)col * 48];
    atomicAdd(&acc1[r6][c],      v * __half2float(src[c]));
    atomicAdd(&acc1[r6][c + 16], v * __half2float(src[c + 16]));
    atomicAdd(&acc1[r6][c + 32], v * __half2float(src[c + 32]));
  }
  j1 = brp2[b + 1];
  for (int j = brp2[b] + g; j < j1; j += 16) {
    int2 cv = pack2[j];
    int col = cv.x & 0xFFFF, r6 = (cv.x >> 16) & 63;
    float v = __int_as_float(cv.y);
    const __half* src = &Pa2[(size_t)col * 48];
    atomicAdd(&acc2[r6][c],      v * __half2float(src[c]));
    atomicAdd(&acc2[r6][c + 16], v * __half2float(src[c + 16]));
    atomicAdd(&acc2[r6][c + 32], v * __half2float(src[c + 32]));
  }
  __syncthreads();
  const int row0 = b * 64;
  for (int i = tid; i < 64 * 16; i += 256) {
    int r6 = i >> 4, cc = i & 15;
    int row = row0 + r6;
    if (row < n) {
      wsum[(size_t)row * 16 + cc] = s0f[(size_t)row * 16 + cc] + acc1[r6][cc] + acc2[r6][cc];
      m34[(size_t)row * 32 + cc]      = acc1[r6][cc + 16] + acc2[r6][cc + 16];
      m34[(size_t)row * 32 + 16 + cc] = acc1[r6][cc + 32] + acc2[r6][cc + 32];
    }
  }
}

// ---------------- final bucket pass: logits = wsum + A1@m3 + A2@m4; softmax ----------------
__global__ __launch_bounds__(256) void final_bucket(
    const int2* __restrict__ pack1, const int* __restrict__ brp1,
    const int2* __restrict__ pack2, const int* __restrict__ brp2,
    const float* __restrict__ wsum, const float* __restrict__ m34,
    float* __restrict__ out, int n) {
  __shared__ float acc[64][17];
  __shared__ float mrow[64], inv[64];
  const int b = blockIdx.x, tid = threadIdx.x;
  for (int i = tid; i < 64 * 17; i += 256) (&acc[0][0])[i] = 0.f;
  __syncthreads();
  const int g = tid >> 4, c = tid & 15;
  int j1 = brp1[b + 1];
  for (int j = brp1[b] + g; j < j1; j += 16) {
    int2 cv = pack1[j];
    int col = cv.x & 0xFFFF, r6 = (cv.x >> 16) & 63;
    atomicAdd(&acc[r6][c], __int_as_float(cv.y) * m34[(size_t)col * 32 + c]);
  }
  j1 = brp2[b + 1];
  for (int j = brp2[b] + g; j < j1; j += 16) {
    int2 cv = pack2[j];
    int col = cv.x & 0xFFFF, r6 = (cv.x >> 16) & 63;
    atomicAdd(&acc[r6][c], __int_as_float(cv.y) * m34[(size_t)col * 32 + 16 + c]);
  }
  __syncthreads();
  const int row0 = b * 64;
  if (tid < 64) {
    int row = row0 + tid;
    if (row < n) {
      float mx = -1e30f, s = 0.f;
#pragma unroll
      for (int k = 0; k < 16; ++k) {
        float l = wsum[(size_t)row * 16 + k] + acc[tid][k];
        acc[tid][k] = l;
        mx = fmaxf(mx, l);
      }
#pragma unroll
      for (int k = 0; k < 16; ++k) s += __expf(acc[tid][k] - mx);
      mrow[tid] = mx;
      inv[tid] = 1.f / s;
    }
  }
  __syncthreads();
  for (int i = tid; i < 64 * 16; i += 256) {
    int r6 = i >> 4, cc = i & 15, row = row0 + r6;
    if (row < n) out[(size_t)row * 16 + cc] = __expf(acc[r6][cc] - mrow[r6]) * inv[r6];
  }
}

extern "C" void kernel_launch(void* const* d_in, const int* in_sizes, int n_in,
                              void* d_out, int out_size, void* d_ws, size_t ws_size,
                              hipStream_t stream) {
  const float* x   = (const float*)d_in[0];
  const int*   a1r = (const int*)d_in[1];
  const int*   a1c = (const int*)d_in[2];
  const float* a1v = (const float*)d_in[3];
  const int*   a2r = (const int*)d_in[4];
  const int*   a2c = (const int*)d_in[5];
  const float* a2v = (const float*)d_in[6];
  const float* we  = (const float*)d_in[7];
  const float* wc  = (const float*)d_in[8];
  const int n  = in_sizes[0] / INF;   // 50000 (must be <= 65536 for 16-bit col pack)
  const int e1 = in_sizes[1];         // 1,000,000
  const int e2 = in_sizes[4];         // 1,500,000
  const int nbk = (n + 63) >> 6;      // 782 buckets

  // ---- workspace layout (~69 MB) ----
  char* w = (char*)d_ws;
  size_t off = 0;
  unsigned short* r0h = (unsigned short*)(w + off); off += (size_t)n * HID * 2;     // 12.8 MB
  unsigned short* r0l = (unsigned short*)(w + off); off += (size_t)n * HID * 2;     // 12.8 MB
  float* s0f  = (float*)(w + off); off += (size_t)n * 16 * 4;                       //  3.2 MB
  __half* Pa1h = (__half*)(w + off); off += (size_t)n * 48 * 2;                     //  4.8 MB
  __half* Pa2h = (__half*)(w + off); off += (size_t)n * 48 * 2;                     //  4.8 MB
  float* wsum = (float*)(w + off); off += (size_t)n * 16 * 4;                       //  3.2 MB
  float* m34  = (float*)(w + off); off += (size_t)n * 32 * 4;                       //  6.4 MB
  int2* pack1 = (int2*)(w + off);  off += (size_t)e1 * 8;                           //  8 MB
  int2* pack2 = (int2*)(w + off);  off += (size_t)e2 * 8;                           // 12 MB
  unsigned short* wefh = (unsigned short*)(w + off); off += (size_t)512 * HID * 2;  // 128 KB
  unsigned short* wefl = (unsigned short*)(w + off); off += (size_t)512 * HID * 2;  // 128 KB
  unsigned short* wcfh = (unsigned short*)(w + off); off += (size_t)HID * PW * 2;   //  28 KB
  unsigned short* wcfl = (unsigned short*)(w + off); off += (size_t)HID * PW * 2;   //  28 KB
  int* bcnt1  = (int*)(w + off); off += (size_t)NBKMAX * 4;   // zeroed each call (adjacent pair)
  int* bcnt2  = (int*)(w + off); off += (size_t)NBKMAX * 4;
  int* brp1   = (int*)(w + off); off += (size_t)(NBKMAX + 1) * 4;
  int* brp2   = (int*)(w + off); off += (size_t)(NBKMAX + 1) * 4;
  int* btail1 = (int*)(w + off); off += (size_t)NBKMAX * 16 * 4;  // padded: 1 counter / 64B
  int* btail2 = (int*)(w + off); off += (size_t)NBKMAX * 16 * 4;

  hipMemsetAsync(bcnt1, 0, (size_t)2 * NBKMAX * sizeof(int), stream);

  prep_w<<<312, 256, 0, stream>>>(we, wc, wefh, wefl, wcfh, wcfl);
  embed_mfma<<<(n + 63) / 64, 128, 0, stream>>>(x, wefh, wefl, r0h, r0l, n);
  proj_mfma<<<(n + 63) / 64, 128, 0, stream>>>(r0h, r0l, wcfh, wcfl, s0f, Pa1h, Pa2h, n);

  hist_buckets<<<64, 256, 0, stream>>>(a1r, e1, a2r, e2, bcnt1, bcnt2, nbk);
  scan_buckets<<<2, 256, 0, stream>>>(bcnt1, brp1, btail1, bcnt2, brp2, btail2, nbk);
  scatter_edges<<<(e1 + e2 + 255) / 256, 256, 0, stream>>>(
      a1r, a1c, a1v, e1, a2r, a2c, a2v, e2, btail1, pack1, btail2, pack2);

  spmm_bucket48<<<nbk, 256, 0, stream>>>(
      pack1, brp1, pack2, brp2, Pa1h, Pa2h, s0f, wsum, m34, n);
  final_bucket<<<nbk, 256, 0, stream>>>(
      pack1, brp1, pack2, brp2, wsum, m34, (float*)d_out, n);
}

// Round 6
// 433.899 us; speedup vs baseline: 3.0064x; 3.0064x over previous
//
#include <hip/hip_runtime.h>
#include <hip/hip_fp16.h>

#define HID 128
#define INF 500
#define NCLS 16
#define PW  112    // projected width: [s0 | p1 q3a q4a | p2 q3b q4b]
#define NBKMAX 1024

typedef __attribute__((ext_vector_type(8))) short short8v;
typedef __attribute__((ext_vector_type(4))) float f32x4;

// split fp32 into hi (truncated bf16) + lo (bf16 of remainder)
__device__ __forceinline__ void split_bf16(float v, unsigned short& h, unsigned short& l) {
  unsigned u = __float_as_uint(v);
  h = (unsigned short)(u >> 16);
  float hf = __uint_as_float(u & 0xFFFF0000u);
  l = (unsigned short)(__float_as_uint(v - hf) >> 16);
}

__device__ __forceinline__ void cvt8(float4 c0, float4 c1, short8v& h8, short8v& l8) {
  float va[8] = {c0.x, c0.y, c0.z, c0.w, c1.x, c1.y, c1.z, c1.w};
#pragma unroll
  for (int j = 0; j < 8; ++j) {
    unsigned short h, l;
    split_bf16(va[j], h, l);
    h8[j] = (short)h;
    l8[j] = (short)l;
  }
}

// ---------------- weight prep: fragment-linear hi/lo bf16 planes ----------------
__global__ __launch_bounds__(256) void prep_w(
    const float* __restrict__ we, const float* __restrict__ wc,
    unsigned short* __restrict__ wh, unsigned short* __restrict__ wl,
    unsigned short* __restrict__ ch, unsigned short* __restrict__ cl) {
  const int bid = blockIdx.x;
  if (bid < 256) {
    int idx = bid * 256 + threadIdx.x;     // < 512*128
    int k = idx >> 7, nn = idx & 127;
    float v = (k < INF) ? we[k * HID + nn] : 0.f;
    unsigned short h, l;
    split_bf16(v, h, l);
    int kstep = k >> 5, ks = k & 31;
    int lane = (nn & 15) | ((ks >> 3) << 4);
    int j = ks & 7, nf = nn >> 4;
    size_t o = (((size_t)(kstep * 8 + nf)) * 64 + lane) * 8 + j;
    wh[o] = h;
    wl[o] = l;
  } else {
    int idx = (bid - 256) * 256 + threadIdx.x;
    if (idx >= HID * PW) return;
    int k = idx / PW, np = idx % PW;
    int o = np >> 4;
    int blk = (o == 0) ? 0 : ((o < 4) ? (2 * o - 1) : (2 * o - 6));
    float v = wc[(blk * HID + k) * NCLS + (np & 15)];
    unsigned short h, l;
    split_bf16(v, h, l);
    int kstep = k >> 5, ks = k & 31;
    int lane = (np & 15) | ((ks >> 3) << 4);
    int j = ks & 7, nf = np >> 4;
    size_t of = (((size_t)(kstep * 7 + nf)) * 64 + lane) * 8 + j;
    ch[of] = h;
    cl[of] = l;
  }
}

// ---------------- embed MFMA: r0 = relu(x @ we), bf16x3, no LDS ----------------
__global__ __launch_bounds__(128) void embed_mfma(
    const float* __restrict__ x, const unsigned short* __restrict__ wh,
    const unsigned short* __restrict__ wl, unsigned short* __restrict__ r0h,
    unsigned short* __restrict__ r0l, int n) {
  const int wave = threadIdx.x >> 6, lane = threadIdx.x & 63;
  const int row0 = blockIdx.x * 64 + wave * 32;
  const int rA = lane & 15, kg = lane >> 4;

  f32x4 acc[2][8];
#pragma unroll
  for (int rf = 0; rf < 2; ++rf)
#pragma unroll
    for (int nf = 0; nf < 8; ++nf)
#pragma unroll
      for (int r = 0; r < 4; ++r) acc[rf][nf][r] = 0.f;

  const float* xr0 = &x[(size_t)min(row0 + rA, n - 1) * INF];
  const float* xr1 = &x[(size_t)min(row0 + 16 + rA, n - 1) * INF];

  for (int kstep = 0; kstep < 16; ++kstep) {
    const int kb = kstep * 32 + kg * 8;
    const bool v0 = (kb + 4 <= INF), v1 = (kb + 8 <= INF);
    const int ka0 = v0 ? kb : 0, ka1 = v1 ? kb + 4 : 0;
    float4 z4 = make_float4(0.f, 0.f, 0.f, 0.f);
    float4 a0c0 = *(const float4*)&xr0[ka0]; if (!v0) a0c0 = z4;
    float4 a0c1 = *(const float4*)&xr0[ka1]; if (!v1) a0c1 = z4;
    float4 a1c0 = *(const float4*)&xr1[ka0]; if (!v0) a1c0 = z4;
    float4 a1c1 = *(const float4*)&xr1[ka1]; if (!v1) a1c1 = z4;

    short8v ah[2], al[2];
    cvt8(a0c0, a0c1, ah[0], al[0]);
    cvt8(a1c0, a1c1, ah[1], al[1]);

    const size_t bbase = ((size_t)kstep * 8 * 64 + lane) * 8;
    short8v Bh[8], Bl[8];
#pragma unroll
    for (int nf = 0; nf < 8; ++nf) {
      Bh[nf] = *(const short8v*)&wh[bbase + (size_t)nf * 512];
      Bl[nf] = *(const short8v*)&wl[bbase + (size_t)nf * 512];
    }
#pragma unroll
    for (int rf = 0; rf < 2; ++rf)
#pragma unroll
      for (int nf = 0; nf < 8; ++nf) {
        acc[rf][nf] = __builtin_amdgcn_mfma_f32_16x16x32_bf16(ah[rf], Bh[nf], acc[rf][nf], 0, 0, 0);
        acc[rf][nf] = __builtin_amdgcn_mfma_f32_16x16x32_bf16(ah[rf], Bl[nf], acc[rf][nf], 0, 0, 0);
        acc[rf][nf] = __builtin_amdgcn_mfma_f32_16x16x32_bf16(al[rf], Bh[nf], acc[rf][nf], 0, 0, 0);
      }
  }

#pragma unroll
  for (int rf = 0; rf < 2; ++rf)
#pragma unroll
    for (int nf = 0; nf < 8; ++nf) {
      const int row = row0 + rf * 16 + kg * 4;
      const int col = nf * 16 + rA;
#pragma unroll
      for (int r = 0; r < 4; ++r) {
        if (row + r < n) {
          float v = fmaxf(acc[rf][nf][r], 0.f);
          unsigned short h, l;
          split_bf16(v, h, l);
          r0h[(size_t)(row + r) * HID + col] = h;
          r0l[(size_t)(row + r) * HID + col] = l;
        }
      }
    }
}

// ---------------- proj MFMA: [s0|Pa1|Pa2] = r0 @ wcP, bf16x3, K=128 ----------------
// nf0 -> s0f fp32 [n][16]; nf1..3 -> Pa1 fp16 [n][16][4] slot nf-1 (slot3=0);
// nf4..6 -> Pa2 fp16 [n][16][4] slot nf-4 (slot3=0)
__global__ __launch_bounds__(128) void proj_mfma(
    const unsigned short* __restrict__ r0h, const unsigned short* __restrict__ r0l,
    const unsigned short* __restrict__ ch, const unsigned short* __restrict__ cl,
    float* __restrict__ s0f, __half* __restrict__ Pa1, __half* __restrict__ Pa2, int n) {
  const int wave = threadIdx.x >> 6, lane = threadIdx.x & 63;
  const int row0 = blockIdx.x * 64 + wave * 32;
  const int rA = lane & 15, kg = lane >> 4;

  f32x4 acc[2][7];
#pragma unroll
  for (int rf = 0; rf < 2; ++rf)
#pragma unroll
    for (int nf = 0; nf < 7; ++nf)
#pragma unroll
      for (int r = 0; r < 4; ++r) acc[rf][nf][r] = 0.f;

  const unsigned short* a0h = &r0h[(size_t)min(row0 + rA, n - 1) * HID];
  const unsigned short* a0l = &r0l[(size_t)min(row0 + rA, n - 1) * HID];
  const unsigned short* a1h = &r0h[(size_t)min(row0 + 16 + rA, n - 1) * HID];
  const unsigned short* a1l = &r0l[(size_t)min(row0 + 16 + rA, n - 1) * HID];

#pragma unroll
  for (int kstep = 0; kstep < 4; ++kstep) {
    const int kb = kstep * 32 + kg * 8;
    short8v ah[2], al[2];
    ah[0] = *(const short8v*)&a0h[kb];
    al[0] = *(const short8v*)&a0l[kb];
    ah[1] = *(const short8v*)&a1h[kb];
    al[1] = *(const short8v*)&a1l[kb];

    const size_t bbase = ((size_t)kstep * 7 * 64 + lane) * 8;
    short8v Bh[7], Bl[7];
#pragma unroll
    for (int nf = 0; nf < 7; ++nf) {
      Bh[nf] = *(const short8v*)&ch[bbase + (size_t)nf * 512];
      Bl[nf] = *(const short8v*)&cl[bbase + (size_t)nf * 512];
    }
#pragma unroll
    for (int rf = 0; rf < 2; ++rf)
#pragma unroll
      for (int nf = 0; nf < 7; ++nf) {
        acc[rf][nf] = __builtin_amdgcn_mfma_f32_16x16x32_bf16(ah[rf], Bh[nf], acc[rf][nf], 0, 0, 0);
        acc[rf][nf] = __builtin_amdgcn_mfma_f32_16x16x32_bf16(ah[rf], Bl[nf], acc[rf][nf], 0, 0, 0);
        acc[rf][nf] = __builtin_amdgcn_mfma_f32_16x16x32_bf16(al[rf], Bh[nf], acc[rf][nf], 0, 0, 0);
      }
  }

#pragma unroll
  for (int rf = 0; rf < 2; ++rf)
#pragma unroll
    for (int nf = 0; nf < 7; ++nf) {
      const int row = row0 + rf * 16 + kg * 4;
#pragma unroll
      for (int r = 0; r < 4; ++r) {
        if (row + r < n) {
          float v = acc[rf][nf][r];
          size_t ro = (size_t)(row + r) * 16 + rA;
          if (nf == 0) {
            s0f[ro] = v;
          } else if (nf < 4) {
            Pa1[ro * 4 + (nf - 1)] = __float2half(v);
            if (nf == 1) Pa1[ro * 4 + 3] = __float2half(0.f);
          } else {
            Pa2[ro * 4 + (nf - 4)] = __float2half(v);
            if (nf == 4) Pa2[ro * 4 + 3] = __float2half(0.f);
          }
        }
      }
    }
}

// ---------------- bucket CSR build (64 rows per bucket) ----------------
__global__ __launch_bounds__(256) void hist_buckets(
    const int* __restrict__ r1, int e1, const int* __restrict__ r2, int e2,
    int* __restrict__ bcnt1, int* __restrict__ bcnt2, int nbk) {
  __shared__ int h1[NBKMAX], h2[NBKMAX];
  for (int i = threadIdx.x; i < NBKMAX; i += 256) { h1[i] = 0; h2[i] = 0; }
  __syncthreads();
  const int total = e1 + e2;
  for (int i = blockIdx.x * 256 + threadIdx.x; i < total; i += gridDim.x * 256) {
    if (i < e1) atomicAdd(&h1[r1[i] >> 6], 1);
    else atomicAdd(&h2[r2[i - e1] >> 6], 1);
  }
  __syncthreads();
  for (int i = threadIdx.x; i < nbk; i += 256) {
    if (h1[i]) atomicAdd(&bcnt1[i], h1[i]);
    if (h2[i]) atomicAdd(&bcnt2[i], h2[i]);
  }
}

// scan bucket counts -> brp + padded tail counters (stride 16 ints = 64B)
__global__ __launch_bounds__(256) void scan_buckets(
    const int* __restrict__ bcnt1, int* __restrict__ brp1, int* __restrict__ btail1,
    const int* __restrict__ bcnt2, int* __restrict__ brp2, int* __restrict__ btail2,
    int nbk) {
  const int* bc = blockIdx.x ? bcnt2 : bcnt1;
  int* rp = blockIdx.x ? brp2 : brp1;
  int* bt = blockIdx.x ? btail2 : btail1;
  __shared__ int sh[256];
  const int t = threadIdx.x;
  const int chunk = (nbk + 255) >> 8;
  const int lo = t * chunk;
  const int hi = min(lo + chunk, nbk);
  int s = 0;
  for (int i = lo; i < hi; ++i) s += bc[i];
  sh[t] = s;
  __syncthreads();
  for (int d = 1; d < 256; d <<= 1) {
    int v = (t >= d) ? sh[t - d] : 0;
    __syncthreads();
    sh[t] += v;
    __syncthreads();
  }
  int run = sh[t] - s;
  for (int i = lo; i < hi; ++i) { rp[i] = run; bt[i * 16] = run; run += bc[i]; }
  if (t == 255) rp[nbk] = sh[255];
}

// scatter edges into bucket-grouped pack; .x = col | (row%64)<<16  (requires n <= 65536)
__global__ void scatter_edges(
    const int* __restrict__ r1, const int* __restrict__ c1, const float* __restrict__ v1, int e1,
    const int* __restrict__ r2, const int* __restrict__ c2, const float* __restrict__ v2, int e2,
    int* __restrict__ btail1, int2* __restrict__ pack1,
    int* __restrict__ btail2, int2* __restrict__ pack2) {
  int i = blockIdx.x * blockDim.x + threadIdx.x;
  if (i < e1) {
    int r = r1[i];
    int pos = atomicAdd(&btail1[(r >> 6) << 4], 1);
    pack1[pos] = make_int2(c1[i] | ((r & 63) << 16), __float_as_int(v1[i]));
  } else if (i < e1 + e2) {
    int k = i - e1;
    int r = r2[k];
    int pos = atomicAdd(&btail2[(r >> 6) << 4], 1);
    pack2[pos] = make_int2(c2[k] | ((r & 63) << 16), __float_as_int(v2[k]));
  }
}

// per-bucket LDS counting sort -> row-sorted edge list + per-row rp
__global__ __launch_bounds__(256) void bucket_sort(
    const int2* __restrict__ pack1, const int* __restrict__ brp1,
    int2* __restrict__ srt1, int* __restrict__ rp1,
    const int2* __restrict__ pack2, const int* __restrict__ brp2,
    int2* __restrict__ srt2, int* __restrict__ rp2, int n, int nbk) {
  const int b = blockIdx.x;
  const int2* pack = blockIdx.y ? pack2 : pack1;
  const int* brp = blockIdx.y ? brp2 : brp1;
  int2* srt = blockIdx.y ? srt2 : srt1;
  int* rp = blockIdx.y ? rp2 : rp1;
  __shared__ int lcnt[64], lofs[64], lcur[64];
  const int tid = threadIdx.x;
  if (tid < 64) lcnt[tid] = 0;
  __syncthreads();
  const int base = brp[b], ecnt = brp[b + 1] - base;
  for (int i = tid; i < ecnt; i += 256)
    atomicAdd(&lcnt[(pack[base + i].x >> 16) & 63], 1);
  __syncthreads();
  if (tid == 0) {
    int run = 0;
    for (int r = 0; r < 64; ++r) { lofs[r] = run; run += lcnt[r]; }
  }
  __syncthreads();
  if (tid < 64) {
    lcur[tid] = lofs[tid];
    int row = b * 64 + tid;
    if (row < n) rp[row] = base + lofs[tid];
  }
  if (b == nbk - 1 && tid == 0) rp[n] = brp[nbk];
  __syncthreads();
  for (int i = tid; i < ecnt; i += 256) {
    int2 e = pack[base + i];
    int r6 = (e.x >> 16) & 63;
    int pos = base + atomicAdd(&lcur[r6], 1);
    srt[pos] = make_int2(e.x & 0xFFFF, e.y);
  }
}

// ---------------- fused SpMM (both matrices, 48-wide) + combine ----------------
// wave per row: wsum = s0 + A1@p1 + A2@p2 ; m34p[row][c] = {A1@q3a+A2@q3b, A1@q4a+A2@q4b}
__global__ __launch_bounds__(256) void spmm48_both(
    const int2* __restrict__ srt1, const int* __restrict__ rp1,
    const int2* __restrict__ srt2, const int* __restrict__ rp2,
    const __half* __restrict__ Pa1, const __half* __restrict__ Pa2,
    const float* __restrict__ s0f, float* __restrict__ wsum,
    float* __restrict__ m34p, int n) {
  const int row = blockIdx.x * 4 + (threadIdx.x >> 6);
  if (row >= n) return;
  const int lane = threadIdx.x & 63;
  const int c = lane & 15, g = lane >> 4;
  float a0 = 0.f, a1 = 0.f, a2 = 0.f, b0 = 0.f, b1 = 0.f, b2 = 0.f;
  int j1 = rp1[row + 1];
  for (int j = rp1[row] + g; j < j1; j += 4) {
    int2 e = srt1[j];
    float v = __int_as_float(e.y);
    float2 raw = *(const float2*)(Pa1 + ((size_t)e.x * 16 + c) * 4);
    float2 f0 = __half22float2(*(__half2*)&raw.x);
    float2 f1 = __half22float2(*(__half2*)&raw.y);
    a0 += v * f0.x; a1 += v * f0.y; a2 += v * f1.x;
  }
  j1 = rp2[row + 1];
  for (int j = rp2[row] + g; j < j1; j += 4) {
    int2 e = srt2[j];
    float v = __int_as_float(e.y);
    float2 raw = *(const float2*)(Pa2 + ((size_t)e.x * 16 + c) * 4);
    float2 f0 = __half22float2(*(__half2*)&raw.x);
    float2 f1 = __half22float2(*(__half2*)&raw.y);
    b0 += v * f0.x; b1 += v * f0.y; b2 += v * f1.x;
  }
  a0 += __shfl_xor(a0, 16); a0 += __shfl_xor(a0, 32);
  a1 += __shfl_xor(a1, 16); a1 += __shfl_xor(a1, 32);
  a2 += __shfl_xor(a2, 16); a2 += __shfl_xor(a2, 32);
  b0 += __shfl_xor(b0, 16); b0 += __shfl_xor(b0, 32);
  b1 += __shfl_xor(b1, 16); b1 += __shfl_xor(b1, 32);
  b2 += __shfl_xor(b2, 16); b2 += __shfl_xor(b2, 32);
  if (g == 0) {
    size_t ro = (size_t)row * 16 + c;
    wsum[ro] = s0f[ro] + a0 + b0;
    *(float2*)&m34p[ro * 2] = make_float2(a1 + b1, a2 + b2);
  }
}

// ---------------- final: logits = wsum + A1@m3 + A2@m4; softmax ----------------
__global__ __launch_bounds__(256) void final_spmm_softmax(
    const int2* __restrict__ srt1, const int* __restrict__ rp1,
    const int2* __restrict__ srt2, const int* __restrict__ rp2,
    const float* __restrict__ wsum, const float* __restrict__ m34p,
    float* __restrict__ out, int n) {
  const int row = blockIdx.x * 4 + (threadIdx.x >> 6);
  if (row >= n) return;
  const int lane = threadIdx.x & 63;
  const int c = lane & 15, g = lane >> 4;
  float accA = 0.f, accB = 0.f;
  int j1 = rp1[row + 1];
  for (int j = rp1[row] + g; j < j1; j += 4) {
    int2 e = srt1[j];
    float2 mv = *(const float2*)&m34p[((size_t)e.x * 16 + c) * 2];
    accA += __int_as_float(e.y) * mv.x;
  }
  j1 = rp2[row + 1];
  for (int j = rp2[row] + g; j < j1; j += 4) {
    int2 e = srt2[j];
    float2 mv = *(const float2*)&m34p[((size_t)e.x * 16 + c) * 2];
    accB += __int_as_float(e.y) * mv.y;
  }
  accA += __shfl_xor(accA, 16); accA += __shfl_xor(accA, 32);
  accB += __shfl_xor(accB, 16); accB += __shfl_xor(accB, 32);
  float logit = wsum[(size_t)row * 16 + c] + accA + accB;
  float m = logit;
#pragma unroll
  for (int off = 1; off < 16; off <<= 1) m = fmaxf(m, __shfl_xor(m, off));
  float e = __expf(logit - m);
  float s = e;
#pragma unroll
  for (int off = 1; off < 16; off <<= 1) s += __shfl_xor(s, off);
  float p = e / s;
  if (lane < 16) out[(size_t)row * NCLS + lane] = p;
}

extern "C" void kernel_launch(void* const* d_in, const int* in_sizes, int n_in,
                              void* d_out, int out_size, void* d_ws, size_t ws_size,
                              hipStream_t stream) {
  const float* x   = (const float*)d_in[0];
  const int*   a1r = (const int*)d_in[1];
  const int*   a1c = (const int*)d_in[2];
  const float* a1v = (const float*)d_in[3];
  const int*   a2r = (const int*)d_in[4];
  const int*   a2c = (const int*)d_in[5];
  const float* a2v = (const float*)d_in[6];
  const float* we  = (const float*)d_in[7];
  const float* wc  = (const float*)d_in[8];
  const int n  = in_sizes[0] / INF;   // 50000 (<= 65536 for 16-bit col pack)
  const int e1 = in_sizes[1];         // 1,000,000
  const int e2 = in_sizes[4];         // 1,500,000
  const int nbk = (n + 63) >> 6;      // 782 buckets

  // ---- workspace layout (~92 MB) ----
  char* w = (char*)d_ws;
  size_t off = 0;
  unsigned short* r0h = (unsigned short*)(w + off); off += (size_t)n * HID * 2;     // 12.8 MB
  unsigned short* r0l = (unsigned short*)(w + off); off += (size_t)n * HID * 2;     // 12.8 MB
  float* s0f  = (float*)(w + off); off += (size_t)n * 16 * 4;                       //  3.2 MB
  __half* Pa1 = (__half*)(w + off); off += (size_t)n * 64 * 2;                      //  6.4 MB
  __half* Pa2 = (__half*)(w + off); off += (size_t)n * 64 * 2;                      //  6.4 MB
  float* wsum = (float*)(w + off); off += (size_t)n * 16 * 4;                       //  3.2 MB
  float* m34p = (float*)(w + off); off += (size_t)n * 32 * 4;                       //  6.4 MB
  int2* pack1 = (int2*)(w + off);  off += (size_t)e1 * 8;                           //  8 MB
  int2* pack2 = (int2*)(w + off);  off += (size_t)e2 * 8;                           // 12 MB
  int2* srt1  = (int2*)(w + off);  off += (size_t)e1 * 8;                           //  8 MB
  int2* srt2  = (int2*)(w + off);  off += (size_t)e2 * 8;                           // 12 MB
  unsigned short* wefh = (unsigned short*)(w + off); off += (size_t)512 * HID * 2;  // 128 KB
  unsigned short* wefl = (unsigned short*)(w + off); off += (size_t)512 * HID * 2;  // 128 KB
  unsigned short* wcfh = (unsigned short*)(w + off); off += (size_t)HID * PW * 2;   //  28 KB
  unsigned short* wcfl = (unsigned short*)(w + off); off += (size_t)HID * PW * 2;   //  28 KB
  int* bcnt1  = (int*)(w + off); off += (size_t)NBKMAX * 4;   // zeroed (adjacent pair)
  int* bcnt2  = (int*)(w + off); off += (size_t)NBKMAX * 4;
  int* brp1   = (int*)(w + off); off += (size_t)(NBKMAX + 1) * 4;
  int* brp2   = (int*)(w + off); off += (size_t)(NBKMAX + 1) * 4;
  int* btail1 = (int*)(w + off); off += (size_t)NBKMAX * 16 * 4;  // 1 counter / 64B
  int* btail2 = (int*)(w + off); off += (size_t)NBKMAX * 16 * 4;
  int* rp1    = (int*)(w + off); off += (size_t)(n + 1) * 4;
  int* rp2    = (int*)(w + off); off += (size_t)(n + 1) * 4;

  hipMemsetAsync(bcnt1, 0, (size_t)2 * NBKMAX * sizeof(int), stream);

  prep_w<<<312, 256, 0, stream>>>(we, wc, wefh, wefl, wcfh, wcfl);
  embed_mfma<<<(n + 63) / 64, 128, 0, stream>>>(x, wefh, wefl, r0h, r0l, n);
  proj_mfma<<<(n + 63) / 64, 128, 0, stream>>>(r0h, r0l, wcfh, wcfl, s0f, Pa1, Pa2, n);

  hist_buckets<<<64, 256, 0, stream>>>(a1r, e1, a2r, e2, bcnt1, bcnt2, nbk);
  scan_buckets<<<2, 256, 0, stream>>>(bcnt1, brp1, btail1, bcnt2, brp2, btail2, nbk);
  scatter_edges<<<(e1 + e2 + 255) / 256, 256, 0, stream>>>(
      a1r, a1c, a1v, e1, a2r, a2c, a2v, e2, btail1, pack1, btail2, pack2);
  bucket_sort<<<dim3(nbk, 2), 256, 0, stream>>>(
      pack1, brp1, srt1, rp1, pack2, brp2, srt2, rp2, n, nbk);

  spmm48_both<<<(n + 3) / 4, 256, 0, stream>>>(
      srt1, rp1, srt2, rp2, Pa1, Pa2, s0f, wsum, m34p, n);
  final_spmm_softmax<<<(n + 3) / 4, 256, 0, stream>>>(
      srt1, rp1, srt2, rp2, wsum, m34p, (float*)d_out, n);
}

// Round 7
// 349.776 us; speedup vs baseline: 3.7294x; 1.2405x over previous
//
#include <hip/hip_runtime.h>
#include <hip/hip_fp16.h>

#define HID 128
#define INF 500
#define NCLS 16
#define PW  112    // projected width: [s0 | p1 q3a q4a | p2 q3b q4b]
#define BKLG 8
#define BKW 256    // rows per bucket
#define NB1 128    // partition blocks, matrix 1
#define NB2 192    // partition blocks, matrix 2

typedef __attribute__((ext_vector_type(8))) short short8v;
typedef __attribute__((ext_vector_type(4))) float f32x4;

// split fp32 into hi (truncated bf16) + lo (bf16 of remainder)
__device__ __forceinline__ void split_bf16(float v, unsigned short& h, unsigned short& l) {
  unsigned u = __float_as_uint(v);
  h = (unsigned short)(u >> 16);
  float hf = __uint_as_float(u & 0xFFFF0000u);
  l = (unsigned short)(__float_as_uint(v - hf) >> 16);
}

__device__ __forceinline__ void cvt8(float4 c0, float4 c1, short8v& h8, short8v& l8) {
  float va[8] = {c0.x, c0.y, c0.z, c0.w, c1.x, c1.y, c1.z, c1.w};
#pragma unroll
  for (int j = 0; j < 8; ++j) {
    unsigned short h, l;
    split_bf16(va[j], h, l);
    h8[j] = (short)h;
    l8[j] = (short)l;
  }
}

// ---------------- weight prep: fragment-linear hi/lo bf16 planes ----------------
__global__ __launch_bounds__(256) void prep_w(
    const float* __restrict__ we, const float* __restrict__ wc,
    unsigned short* __restrict__ wh, unsigned short* __restrict__ wl,
    unsigned short* __restrict__ ch, unsigned short* __restrict__ cl) {
  const int bid = blockIdx.x;
  if (bid < 256) {
    int idx = bid * 256 + threadIdx.x;     // < 512*128
    int k = idx >> 7, nn = idx & 127;
    float v = (k < INF) ? we[k * HID + nn] : 0.f;
    unsigned short h, l;
    split_bf16(v, h, l);
    int kstep = k >> 5, ks = k & 31;
    int lane = (nn & 15) | ((ks >> 3) << 4);
    int j = ks & 7, nf = nn >> 4;
    size_t o = (((size_t)(kstep * 8 + nf)) * 64 + lane) * 8 + j;
    wh[o] = h;
    wl[o] = l;
  } else {
    int idx = (bid - 256) * 256 + threadIdx.x;
    if (idx >= HID * PW) return;
    int k = idx / PW, np = idx % PW;
    int o = np >> 4;
    int blk = (o == 0) ? 0 : ((o < 4) ? (2 * o - 1) : (2 * o - 6));
    float v = wc[(blk * HID + k) * NCLS + (np & 15)];
    unsigned short h, l;
    split_bf16(v, h, l);
    int kstep = k >> 5, ks = k & 31;
    int lane = (np & 15) | ((ks >> 3) << 4);
    int j = ks & 7, nf = np >> 4;
    size_t of = (((size_t)(kstep * 7 + nf)) * 64 + lane) * 8 + j;
    ch[of] = h;
    cl[of] = l;
  }
}

// ---------------- embed MFMA: r0 = relu(x @ we), bf16x3, no LDS ----------------
__global__ __launch_bounds__(128) void embed_mfma(
    const float* __restrict__ x, const unsigned short* __restrict__ wh,
    const unsigned short* __restrict__ wl, unsigned short* __restrict__ r0h,
    unsigned short* __restrict__ r0l, int n) {
  const int wave = threadIdx.x >> 6, lane = threadIdx.x & 63;
  const int row0 = blockIdx.x * 64 + wave * 32;
  const int rA = lane & 15, kg = lane >> 4;

  f32x4 acc[2][8];
#pragma unroll
  for (int rf = 0; rf < 2; ++rf)
#pragma unroll
    for (int nf = 0; nf < 8; ++nf)
#pragma unroll
      for (int r = 0; r < 4; ++r) acc[rf][nf][r] = 0.f;

  const float* xr0 = &x[(size_t)min(row0 + rA, n - 1) * INF];
  const float* xr1 = &x[(size_t)min(row0 + 16 + rA, n - 1) * INF];

  for (int kstep = 0; kstep < 16; ++kstep) {
    const int kb = kstep * 32 + kg * 8;
    const bool v0 = (kb + 4 <= INF), v1 = (kb + 8 <= INF);
    const int ka0 = v0 ? kb : 0, ka1 = v1 ? kb + 4 : 0;
    float4 z4 = make_float4(0.f, 0.f, 0.f, 0.f);
    float4 a0c0 = *(const float4*)&xr0[ka0]; if (!v0) a0c0 = z4;
    float4 a0c1 = *(const float4*)&xr0[ka1]; if (!v1) a0c1 = z4;
    float4 a1c0 = *(const float4*)&xr1[ka0]; if (!v0) a1c0 = z4;
    float4 a1c1 = *(const float4*)&xr1[ka1]; if (!v1) a1c1 = z4;

    short8v ah[2], al[2];
    cvt8(a0c0, a0c1, ah[0], al[0]);
    cvt8(a1c0, a1c1, ah[1], al[1]);

    const size_t bbase = ((size_t)kstep * 8 * 64 + lane) * 8;
    short8v Bh[8], Bl[8];
#pragma unroll
    for (int nf = 0; nf < 8; ++nf) {
      Bh[nf] = *(const short8v*)&wh[bbase + (size_t)nf * 512];
      Bl[nf] = *(const short8v*)&wl[bbase + (size_t)nf * 512];
    }
#pragma unroll
    for (int rf = 0; rf < 2; ++rf)
#pragma unroll
      for (int nf = 0; nf < 8; ++nf) {
        acc[rf][nf] = __builtin_amdgcn_mfma_f32_16x16x32_bf16(ah[rf], Bh[nf], acc[rf][nf], 0, 0, 0);
        acc[rf][nf] = __builtin_amdgcn_mfma_f32_16x16x32_bf16(ah[rf], Bl[nf], acc[rf][nf], 0, 0, 0);
        acc[rf][nf] = __builtin_amdgcn_mfma_f32_16x16x32_bf16(al[rf], Bh[nf], acc[rf][nf], 0, 0, 0);
      }
  }

#pragma unroll
  for (int rf = 0; rf < 2; ++rf)
#pragma unroll
    for (int nf = 0; nf < 8; ++nf) {
      const int row = row0 + rf * 16 + kg * 4;
      const int col = nf * 16 + rA;
#pragma unroll
      for (int r = 0; r < 4; ++r) {
        if (row + r < n) {
          float v = fmaxf(acc[rf][nf][r], 0.f);
          unsigned short h, l;
          split_bf16(v, h, l);
          r0h[(size_t)(row + r) * HID + col] = h;
          r0l[(size_t)(row + r) * HID + col] = l;
        }
      }
    }
}

// ---------------- proj MFMA: [s0|Pa1|Pa2] = r0 @ wcP, bf16x3, K=128 ----------------
// nf0 -> s0f fp32 [n][16]; nf1..3 -> Pa1 fp16 [n][16][4] slot nf-1 (slot3=0);
// nf4..6 -> Pa2 fp16 [n][16][4] slot nf-4 (slot3=0)
__global__ __launch_bounds__(128) void proj_mfma(
    const unsigned short* __restrict__ r0h, const unsigned short* __restrict__ r0l,
    const unsigned short* __restrict__ ch, const unsigned short* __restrict__ cl,
    float* __restrict__ s0f, __half* __restrict__ Pa1, __half* __restrict__ Pa2, int n) {
  const int wave = threadIdx.x >> 6, lane = threadIdx.x & 63;
  const int row0 = blockIdx.x * 64 + wave * 32;
  const int rA = lane & 15, kg = lane >> 4;

  f32x4 acc[2][7];
#pragma unroll
  for (int rf = 0; rf < 2; ++rf)
#pragma unroll
    for (int nf = 0; nf < 7; ++nf)
#pragma unroll
      for (int r = 0; r < 4; ++r) acc[rf][nf][r] = 0.f;

  const unsigned short* a0h = &r0h[(size_t)min(row0 + rA, n - 1) * HID];
  const unsigned short* a0l = &r0l[(size_t)min(row0 + rA, n - 1) * HID];
  const unsigned short* a1h = &r0h[(size_t)min(row0 + 16 + rA, n - 1) * HID];
  const unsigned short* a1l = &r0l[(size_t)min(row0 + 16 + rA, n - 1) * HID];

#pragma unroll
  for (int kstep = 0; kstep < 4; ++kstep) {
    const int kb = kstep * 32 + kg * 8;
    short8v ah[2], al[2];
    ah[0] = *(const short8v*)&a0h[kb];
    al[0] = *(const short8v*)&a0l[kb];
    ah[1] = *(const short8v*)&a1h[kb];
    al[1] = *(const short8v*)&a1l[kb];

    const size_t bbase = ((size_t)kstep * 7 * 64 + lane) * 8;
    short8v Bh[7], Bl[7];
#pragma unroll
    for (int nf = 0; nf < 7; ++nf) {
      Bh[nf] = *(const short8v*)&ch[bbase + (size_t)nf * 512];
      Bl[nf] = *(const short8v*)&cl[bbase + (size_t)nf * 512];
    }
#pragma unroll
    for (int rf = 0; rf < 2; ++rf)
#pragma unroll
      for (int nf = 0; nf < 7; ++nf) {
        acc[rf][nf] = __builtin_amdgcn_mfma_f32_16x16x32_bf16(ah[rf], Bh[nf], acc[rf][nf], 0, 0, 0);
        acc[rf][nf] = __builtin_amdgcn_mfma_f32_16x16x32_bf16(ah[rf], Bl[nf], acc[rf][nf], 0, 0, 0);
        acc[rf][nf] = __builtin_amdgcn_mfma_f32_16x16x32_bf16(al[rf], Bh[nf], acc[rf][nf], 0, 0, 0);
      }
  }

#pragma unroll
  for (int rf = 0; rf < 2; ++rf)
#pragma unroll
    for (int nf = 0; nf < 7; ++nf) {
      const int row = row0 + rf * 16 + kg * 4;
#pragma unroll
      for (int r = 0; r < 4; ++r) {
        if (row + r < n) {
          float v = acc[rf][nf][r];
          size_t ro = (size_t)(row + r) * 16 + rA;
          if (nf == 0) {
            s0f[ro] = v;
          } else if (nf < 4) {
            Pa1[ro * 4 + (nf - 1)] = __float2half(v);
            if (nf == 1) Pa1[ro * 4 + 3] = __float2half(0.f);
          } else {
            Pa2[ro * 4 + (nf - 4)] = __float2half(v);
            if (nf == 4) Pa2[ro * 4 + 3] = __float2half(0.f);
          }
        }
      }
    }
}

// ---------------- radix partition: per-block hist -> scan -> per-block scatter ----------------
__global__ __launch_bounds__(256) void part_hist(
    const int* __restrict__ r1, int e1, const int* __restrict__ r2, int e2,
    int* __restrict__ g1, int* __restrict__ g2, int nbk) {
  const int m = blockIdx.y;
  const int NB = m ? NB2 : NB1;
  const int b = blockIdx.x;
  if (b >= NB) return;
  const int* rows = m ? r2 : r1;
  const int E = m ? e2 : e1;
  int* g = m ? g2 : g1;
  __shared__ int h[512];
  for (int i = threadIdx.x; i < nbk; i += 256) h[i] = 0;
  __syncthreads();
  const int ch = (E + NB - 1) / NB;
  const int lo = b * ch, hi = min(lo + ch, E);
  for (int i = lo + threadIdx.x; i < hi; i += 256)
    atomicAdd(&h[rows[i] >> BKLG], 1);
  __syncthreads();
  for (int k = threadIdx.x; k < nbk; k += 256) g[(size_t)k * NB + b] = h[k];
}

__global__ __launch_bounds__(256) void part_scan(
    int* __restrict__ g1, int m1, int* __restrict__ g2, int m2) {
  int* g = blockIdx.x ? g2 : g1;
  const int m = blockIdx.x ? m2 : m1;
  __shared__ int sh[256];
  const int t = threadIdx.x;
  const int chunk = (m + 255) >> 8;
  const int lo = t * chunk, hi = min(lo + chunk, m);
  int s = 0;
  for (int i = lo; i < hi; ++i) s += g[i];
  sh[t] = s;
  __syncthreads();
  for (int d = 1; d < 256; d <<= 1) {
    int v = (t >= d) ? sh[t - d] : 0;
    __syncthreads();
    sh[t] += v;
    __syncthreads();
  }
  int run = sh[t] - s;
  for (int i = lo; i < hi; ++i) { int v = g[i]; g[i] = run; run += v; }
}

// scatter: block b's writes to bucket k form one contiguous run (write-amp ~1x)
__global__ __launch_bounds__(256) void part_scatter(
    const int* __restrict__ r1, const int* __restrict__ c1, const float* __restrict__ v1, int e1,
    const int* __restrict__ r2, const int* __restrict__ c2, const float* __restrict__ v2, int e2,
    const int* __restrict__ g1, const int* __restrict__ g2,
    int2* __restrict__ pack1, int2* __restrict__ pack2, int nbk) {
  const int m = blockIdx.y;
  const int NB = m ? NB2 : NB1;
  const int b = blockIdx.x;
  if (b >= NB) return;
  const int* rows = m ? r2 : r1;
  const int* cols = m ? c2 : c1;
  const float* vals = m ? v2 : v1;
  const int E = m ? e2 : e1;
  const int* g = m ? g2 : g1;
  int2* pack = m ? pack2 : pack1;
  __shared__ int lcur[512];
  for (int k = threadIdx.x; k < nbk; k += 256) lcur[k] = g[(size_t)k * NB + b];
  __syncthreads();
  const int ch = (E + NB - 1) / NB;
  const int lo = b * ch, hi = min(lo + ch, E);
  for (int i = lo + threadIdx.x; i < hi; i += 256) {
    int r = rows[i];
    int pos = atomicAdd(&lcur[r >> BKLG], 1);
    pack[pos] = make_int2(cols[i] | ((r & (BKW - 1)) << 16), __float_as_int(vals[i]));
  }
}

// per-bucket LDS counting sort (256 rows) -> row-sorted edges + per-row rp
__global__ __launch_bounds__(256) void bucket_sort(
    const int2* __restrict__ pack1, const int* __restrict__ g1,
    int2* __restrict__ srt1, int* __restrict__ rp1, int e1,
    const int2* __restrict__ pack2, const int* __restrict__ g2,
    int2* __restrict__ srt2, int* __restrict__ rp2, int e2,
    int n, int nbk) {
  const int m = blockIdx.y;
  const int NB = m ? NB2 : NB1;
  const int2* pack = m ? pack2 : pack1;
  const int* g = m ? g2 : g1;
  int2* srt = m ? srt2 : srt1;
  int* rp = m ? rp2 : rp1;
  const int E = m ? e2 : e1;
  const int k = blockIdx.x;
  const int base = g[(size_t)k * NB];
  const int end = (k + 1 < nbk) ? g[(size_t)(k + 1) * NB] : E;
  __shared__ int lcnt[256], lws[256], lcur[256];
  const int t = threadIdx.x;
  lcnt[t] = 0;
  __syncthreads();
  for (int i = base + t; i < end; i += 256)
    atomicAdd(&lcnt[(pack[i].x >> 16) & (BKW - 1)], 1);
  __syncthreads();
  int s = lcnt[t];
  lws[t] = s;
  __syncthreads();
  for (int d = 1; d < 256; d <<= 1) {
    int v = (t >= d) ? lws[t - d] : 0;
    __syncthreads();
    lws[t] += v;
    __syncthreads();
  }
  int excl = base + lws[t] - s;
  lcur[t] = excl;
  int row = k * BKW + t;
  if (row < n) rp[row] = excl;
  if (k == nbk - 1 && t == 0) rp[n] = E;
  __syncthreads();
  for (int i = base + t; i < end; i += 256) {
    int2 e = pack[i];
    int pos = atomicAdd(&lcur[(e.x >> 16) & (BKW - 1)], 1);
    srt[pos] = make_int2(e.x & 0xFFFF, e.y);
  }
}

// ---------------- fused SpMM (both matrices, 48-wide) + combine ----------------
__global__ __launch_bounds__(256) void spmm48_both(
    const int2* __restrict__ srt1, const int* __restrict__ rp1,
    const int2* __restrict__ srt2, const int* __restrict__ rp2,
    const __half* __restrict__ Pa1, const __half* __restrict__ Pa2,
    const float* __restrict__ s0f, float* __restrict__ wsum,
    float* __restrict__ m34p, int n) {
  const int row = blockIdx.x * 4 + (threadIdx.x >> 6);
  if (row >= n) return;
  const int lane = threadIdx.x & 63;
  const int c = lane & 15, g = lane >> 4;
  float a0 = 0.f, a1 = 0.f, a2 = 0.f, b0 = 0.f, b1 = 0.f, b2 = 0.f;
  int j1 = rp1[row + 1];
  for (int j = rp1[row] + g; j < j1; j += 4) {
    int2 e = srt1[j];
    float v = __int_as_float(e.y);
    float2 raw = *(const float2*)(Pa1 + ((size_t)e.x * 16 + c) * 4);
    float2 f0 = __half22float2(*(__half2*)&raw.x);
    float2 f1 = __half22float2(*(__half2*)&raw.y);
    a0 += v * f0.x; a1 += v * f0.y; a2 += v * f1.x;
  }
  j1 = rp2[row + 1];
  for (int j = rp2[row] + g; j < j1; j += 4) {
    int2 e = srt2[j];
    float v = __int_as_float(e.y);
    float2 raw = *(const float2*)(Pa2 + ((size_t)e.x * 16 + c) * 4);
    float2 f0 = __half22float2(*(__half2*)&raw.x);
    float2 f1 = __half22float2(*(__half2*)&raw.y);
    b0 += v * f0.x; b1 += v * f0.y; b2 += v * f1.x;
  }
  a0 += __shfl_xor(a0, 16); a0 += __shfl_xor(a0, 32);
  a1 += __shfl_xor(a1, 16); a1 += __shfl_xor(a1, 32);
  a2 += __shfl_xor(a2, 16); a2 += __shfl_xor(a2, 32);
  b0 += __shfl_xor(b0, 16); b0 += __shfl_xor(b0, 32);
  b1 += __shfl_xor(b1, 16); b1 += __shfl_xor(b1, 32);
  b2 += __shfl_xor(b2, 16); b2 += __shfl_xor(b2, 32);
  if (g == 0) {
    size_t ro = (size_t)row * 16 + c;
    wsum[ro] = s0f[ro] + a0 + b0;
    *(float2*)&m34p[ro * 2] = make_float2(a1 + b1, a2 + b2);
  }
}

// ---------------- final: logits = wsum + A1@m3 + A2@m4; softmax ----------------
__global__ __launch_bounds__(256) void final_spmm_softmax(
    const int2* __restrict__ srt1, const int* __restrict__ rp1,
    const int2* __restrict__ srt2, const int* __restrict__ rp2,
    const float* __restrict__ wsum, const float* __restrict__ m34p,
    float* __restrict__ out, int n) {
  const int row = blockIdx.x * 4 + (threadIdx.x >> 6);
  if (row >= n) return;
  const int lane = threadIdx.x & 63;
  const int c = lane & 15, g = lane >> 4;
  float accA = 0.f, accB = 0.f;
  int j1 = rp1[row + 1];
  for (int j = rp1[row] + g; j < j1; j += 4) {
    int2 e = srt1[j];
    float2 mv = *(const float2*)&m34p[((size_t)e.x * 16 + c) * 2];
    accA += __int_as_float(e.y) * mv.x;
  }
  j1 = rp2[row + 1];
  for (int j = rp2[row] + g; j < j1; j += 4) {
    int2 e = srt2[j];
    float2 mv = *(const float2*)&m34p[((size_t)e.x * 16 + c) * 2];
    accB += __int_as_float(e.y) * mv.y;
  }
  accA += __shfl_xor(accA, 16); accA += __shfl_xor(accA, 32);
  accB += __shfl_xor(accB, 16); accB += __shfl_xor(accB, 32);
  float logit = wsum[(size_t)row * 16 + c] + accA + accB;
  float m = logit;
#pragma unroll
  for (int off = 1; off < 16; off <<= 1) m = fmaxf(m, __shfl_xor(m, off));
  float e = __expf(logit - m);
  float s = e;
#pragma unroll
  for (int off = 1; off < 16; off <<= 1) s += __shfl_xor(s, off);
  float p = e / s;
  if (lane < 16) out[(size_t)row * NCLS + lane] = p;
}

extern "C" void kernel_launch(void* const* d_in, const int* in_sizes, int n_in,
                              void* d_out, int out_size, void* d_ws, size_t ws_size,
                              hipStream_t stream) {
  const float* x   = (const float*)d_in[0];
  const int*   a1r = (const int*)d_in[1];
  const int*   a1c = (const int*)d_in[2];
  const float* a1v = (const float*)d_in[3];
  const int*   a2r = (const int*)d_in[4];
  const int*   a2c = (const int*)d_in[5];
  const float* a2v = (const float*)d_in[6];
  const float* we  = (const float*)d_in[7];
  const float* wc  = (const float*)d_in[8];
  const int n  = in_sizes[0] / INF;   // 50000 (<= 65536 for 16-bit col pack)
  const int e1 = in_sizes[1];         // 1,000,000
  const int e2 = in_sizes[4];         // 1,500,000
  const int nbk = (n + BKW - 1) >> BKLG;   // 196 buckets of 256 rows

  // ---- workspace layout (~93 MB) ----
  char* w = (char*)d_ws;
  size_t off = 0;
  unsigned short* r0h = (unsigned short*)(w + off); off += (size_t)n * HID * 2;     // 12.8 MB
  unsigned short* r0l = (unsigned short*)(w + off); off += (size_t)n * HID * 2;     // 12.8 MB
  float* s0f  = (float*)(w + off); off += (size_t)n * 16 * 4;                       //  3.2 MB
  __half* Pa1 = (__half*)(w + off); off += (size_t)n * 64 * 2;                      //  6.4 MB
  __half* Pa2 = (__half*)(w + off); off += (size_t)n * 64 * 2;                      //  6.4 MB
  float* wsum = (float*)(w + off); off += (size_t)n * 16 * 4;                       //  3.2 MB
  float* m34p = (float*)(w + off); off += (size_t)n * 32 * 4;                       //  6.4 MB
  int2* pack1 = (int2*)(w + off);  off += (size_t)e1 * 8;                           //  8 MB
  int2* pack2 = (int2*)(w + off);  off += (size_t)e2 * 8;                           // 12 MB
  int2* srt1  = (int2*)(w + off);  off += (size_t)e1 * 8;                           //  8 MB
  int2* srt2  = (int2*)(w + off);  off += (size_t)e2 * 8;                           // 12 MB
  unsigned short* wefh = (unsigned short*)(w + off); off += (size_t)512 * HID * 2;  // 128 KB
  unsigned short* wefl = (unsigned short*)(w + off); off += (size_t)512 * HID * 2;  // 128 KB
  unsigned short* wcfh = (unsigned short*)(w + off); off += (size_t)HID * PW * 2;   //  28 KB
  unsigned short* wcfl = (unsigned short*)(w + off); off += (size_t)HID * PW * 2;   //  28 KB
  int* g1 = (int*)(w + off); off += (size_t)512 * NB1 * 4;                          // 256 KB
  int* g2 = (int*)(w + off); off += (size_t)512 * NB2 * 4;                          // 384 KB
  int* rp1 = (int*)(w + off); off += (size_t)(n + 1) * 4;
  int* rp2 = (int*)(w + off); off += (size_t)(n + 1) * 4;

  prep_w<<<312, 256, 0, stream>>>(we, wc, wefh, wefl, wcfh, wcfl);
  embed_mfma<<<(n + 63) / 64, 128, 0, stream>>>(x, wefh, wefl, r0h, r0l, n);
  proj_mfma<<<(n + 63) / 64, 128, 0, stream>>>(r0h, r0l, wcfh, wcfl, s0f, Pa1, Pa2, n);

  part_hist<<<dim3(NB2, 2), 256, 0, stream>>>(a1r, e1, a2r, e2, g1, g2, nbk);
  part_scan<<<2, 256, 0, stream>>>(g1, nbk * NB1, g2, nbk * NB2);
  part_scatter<<<dim3(NB2, 2), 256, 0, stream>>>(
      a1r, a1c, a1v, e1, a2r, a2c, a2v, e2, g1, g2, pack1, pack2, nbk);
  bucket_sort<<<dim3(nbk, 2), 256, 0, stream>>>(
      pack1, g1, srt1, rp1, e1, pack2, g2, srt2, rp2, e2, n, nbk);

  spmm48_both<<<(n + 3) / 4, 256, 0, stream>>>(
      srt1, rp1, srt2, rp2, Pa1, Pa2, s0f, wsum, m34p, n);
  final_spmm_softmax<<<(n + 3) / 4, 256, 0, stream>>>(
      srt1, rp1, srt2, rp2, wsum, m34p, (float*)d_out, n);
}

// Round 8
// 335.210 us; speedup vs baseline: 3.8915x; 1.0435x over previous
//
#include <hip/hip_runtime.h>
#include <hip/hip_fp16.h>

#define HID 128
#define INF 500
#define NCLS 16
#define PW  112    // projected width: [s0 | p1 q3a q4a | p2 q3b q4b]
#define BKLG 8
#define BKW 256    // rows per bucket
#define NB1 128    // partition blocks, matrix 1
#define NB2 192    // partition blocks, matrix 2

typedef __attribute__((ext_vector_type(8))) short short8v;
typedef __attribute__((ext_vector_type(4))) float f32x4;

// split fp32 into hi (truncated bf16) + lo (bf16 of remainder)
__device__ __forceinline__ void split_bf16(float v, unsigned short& h, unsigned short& l) {
  unsigned u = __float_as_uint(v);
  h = (unsigned short)(u >> 16);
  float hf = __uint_as_float(u & 0xFFFF0000u);
  l = (unsigned short)(__float_as_uint(v - hf) >> 16);
}

__device__ __forceinline__ void cvt8(float4 c0, float4 c1, short8v& h8, short8v& l8) {
  float va[8] = {c0.x, c0.y, c0.z, c0.w, c1.x, c1.y, c1.z, c1.w};
#pragma unroll
  for (int j = 0; j < 8; ++j) {
    unsigned short h, l;
    split_bf16(va[j], h, l);
    h8[j] = (short)h;
    l8[j] = (short)l;
  }
}

// ---------------- weight prep: fragment-linear hi/lo bf16 planes ----------------
__global__ __launch_bounds__(256) void prep_w(
    const float* __restrict__ we, const float* __restrict__ wc,
    unsigned short* __restrict__ wh, unsigned short* __restrict__ wl,
    unsigned short* __restrict__ ch, unsigned short* __restrict__ cl) {
  const int bid = blockIdx.x;
  if (bid < 256) {
    int idx = bid * 256 + threadIdx.x;     // < 512*128
    int k = idx >> 7, nn = idx & 127;
    float v = (k < INF) ? we[k * HID + nn] : 0.f;
    unsigned short h, l;
    split_bf16(v, h, l);
    int kstep = k >> 5, ks = k & 31;
    int lane = (nn & 15) | ((ks >> 3) << 4);
    int j = ks & 7, nf = nn >> 4;
    size_t o = (((size_t)(kstep * 8 + nf)) * 64 + lane) * 8 + j;
    wh[o] = h;
    wl[o] = l;
  } else {
    int idx = (bid - 256) * 256 + threadIdx.x;
    if (idx >= HID * PW) return;
    int k = idx / PW, np = idx % PW;
    int o = np >> 4;
    int blk = (o == 0) ? 0 : ((o < 4) ? (2 * o - 1) : (2 * o - 6));
    float v = wc[(blk * HID + k) * NCLS + (np & 15)];
    unsigned short h, l;
    split_bf16(v, h, l);
    int kstep = k >> 5, ks = k & 31;
    int lane = (np & 15) | ((ks >> 3) << 4);
    int j = ks & 7, nf = np >> 4;
    size_t of = (((size_t)(kstep * 7 + nf)) * 64 + lane) * 8 + j;
    ch[of] = h;
    cl[of] = l;
  }
}

// ---------------- embed MFMA: r0 = relu(x @ we), bf16x3, 4 waves x 16 rows ----------------
__global__ __launch_bounds__(256) void embed_mfma(
    const float* __restrict__ x, const unsigned short* __restrict__ wh,
    const unsigned short* __restrict__ wl, unsigned short* __restrict__ r0h,
    unsigned short* __restrict__ r0l, int n) {
  const int wave = threadIdx.x >> 6, lane = threadIdx.x & 63;
  const int row0 = blockIdx.x * 64 + wave * 16;
  const int rA = lane & 15, kg = lane >> 4;

  f32x4 acc[8];
#pragma unroll
  for (int nf = 0; nf < 8; ++nf)
#pragma unroll
    for (int r = 0; r < 4; ++r) acc[nf][r] = 0.f;

  const float* xr = &x[(size_t)min(row0 + rA, n - 1) * INF];

  for (int kstep = 0; kstep < 16; ++kstep) {
    const int kb = kstep * 32 + kg * 8;
    const bool v0 = (kb + 4 <= INF), v1 = (kb + 8 <= INF);
    const int ka0 = v0 ? kb : 0, ka1 = v1 ? kb + 4 : 0;
    float4 z4 = make_float4(0.f, 0.f, 0.f, 0.f);
    float4 c0 = *(const float4*)&xr[ka0]; if (!v0) c0 = z4;
    float4 c1 = *(const float4*)&xr[ka1]; if (!v1) c1 = z4;

    short8v ah, al;
    cvt8(c0, c1, ah, al);

    const size_t bbase = ((size_t)kstep * 8 * 64 + lane) * 8;
#pragma unroll
    for (int nf = 0; nf < 8; ++nf) {
      short8v Bh = *(const short8v*)&wh[bbase + (size_t)nf * 512];
      short8v Bl = *(const short8v*)&wl[bbase + (size_t)nf * 512];
      acc[nf] = __builtin_amdgcn_mfma_f32_16x16x32_bf16(ah, Bh, acc[nf], 0, 0, 0);
      acc[nf] = __builtin_amdgcn_mfma_f32_16x16x32_bf16(ah, Bl, acc[nf], 0, 0, 0);
      acc[nf] = __builtin_amdgcn_mfma_f32_16x16x32_bf16(al, Bh, acc[nf], 0, 0, 0);
    }
  }

#pragma unroll
  for (int nf = 0; nf < 8; ++nf) {
    const int row = row0 + kg * 4;
    const int col = nf * 16 + rA;
#pragma unroll
    for (int r = 0; r < 4; ++r) {
      if (row + r < n) {
        float v = fmaxf(acc[nf][r], 0.f);
        unsigned short h, l;
        split_bf16(v, h, l);
        r0h[(size_t)(row + r) * HID + col] = h;
        r0l[(size_t)(row + r) * HID + col] = l;
      }
    }
  }
}

// ---------------- proj MFMA: [s0|Pa1|Pa2] = r0 @ wcP, bf16x3, 4 waves x 16 rows ----------------
__global__ __launch_bounds__(256) void proj_mfma(
    const unsigned short* __restrict__ r0h, const unsigned short* __restrict__ r0l,
    const unsigned short* __restrict__ ch, const unsigned short* __restrict__ cl,
    float* __restrict__ s0f, __half* __restrict__ Pa1, __half* __restrict__ Pa2, int n) {
  const int wave = threadIdx.x >> 6, lane = threadIdx.x & 63;
  const int row0 = blockIdx.x * 64 + wave * 16;
  const int rA = lane & 15, kg = lane >> 4;

  f32x4 acc[7];
#pragma unroll
  for (int nf = 0; nf < 7; ++nf)
#pragma unroll
    for (int r = 0; r < 4; ++r) acc[nf][r] = 0.f;

  const unsigned short* arh = &r0h[(size_t)min(row0 + rA, n - 1) * HID];
  const unsigned short* arl = &r0l[(size_t)min(row0 + rA, n - 1) * HID];

#pragma unroll
  for (int kstep = 0; kstep < 4; ++kstep) {
    const int kb = kstep * 32 + kg * 8;
    short8v ah = *(const short8v*)&arh[kb];
    short8v al = *(const short8v*)&arl[kb];

    const size_t bbase = ((size_t)kstep * 7 * 64 + lane) * 8;
#pragma unroll
    for (int nf = 0; nf < 7; ++nf) {
      short8v Bh = *(const short8v*)&ch[bbase + (size_t)nf * 512];
      short8v Bl = *(const short8v*)&cl[bbase + (size_t)nf * 512];
      acc[nf] = __builtin_amdgcn_mfma_f32_16x16x32_bf16(ah, Bh, acc[nf], 0, 0, 0);
      acc[nf] = __builtin_amdgcn_mfma_f32_16x16x32_bf16(ah, Bl, acc[nf], 0, 0, 0);
      acc[nf] = __builtin_amdgcn_mfma_f32_16x16x32_bf16(al, Bh, acc[nf], 0, 0, 0);
    }
  }

#pragma unroll
  for (int nf = 0; nf < 7; ++nf) {
    const int row = row0 + kg * 4;
#pragma unroll
    for (int r = 0; r < 4; ++r) {
      if (row + r < n) {
        float v = acc[nf][r];
        size_t ro = (size_t)(row + r) * 16 + rA;
        if (nf == 0) {
          s0f[ro] = v;
        } else if (nf < 4) {
          Pa1[ro * 4 + (nf - 1)] = __float2half(v);
          if (nf == 1) Pa1[ro * 4 + 3] = __float2half(0.f);
        } else {
          Pa2[ro * 4 + (nf - 4)] = __float2half(v);
          if (nf == 4) Pa2[ro * 4 + 3] = __float2half(0.f);
        }
      }
    }
  }
}

// ---------------- radix partition: per-block hist -> scan -> per-block scatter ----------------
__global__ __launch_bounds__(256) void part_hist(
    const int* __restrict__ r1, int e1, const int* __restrict__ r2, int e2,
    int* __restrict__ g1, int* __restrict__ g2, int nbk) {
  const int m = blockIdx.y;
  const int NB = m ? NB2 : NB1;
  const int b = blockIdx.x;
  if (b >= NB) return;
  const int* rows = m ? r2 : r1;
  const int E = m ? e2 : e1;
  int* g = m ? g2 : g1;
  __shared__ int h[512];
  for (int i = threadIdx.x; i < nbk; i += 256) h[i] = 0;
  __syncthreads();
  const int ch = (E + NB - 1) / NB;
  const int lo = b * ch, hi = min(lo + ch, E);
  for (int i = lo + threadIdx.x; i < hi; i += 256)
    atomicAdd(&h[rows[i] >> BKLG], 1);
  __syncthreads();
  for (int k = threadIdx.x; k < nbk; k += 256) g[(size_t)k * NB + b] = h[k];
}

__global__ __launch_bounds__(256) void part_scan(
    int* __restrict__ g1, int m1, int* __restrict__ g2, int m2) {
  int* g = blockIdx.x ? g2 : g1;
  const int m = blockIdx.x ? m2 : m1;
  __shared__ int sh[256];
  const int t = threadIdx.x;
  const int chunk = (m + 255) >> 8;
  const int lo = t * chunk, hi = min(lo + chunk, m);
  int s = 0;
  for (int i = lo; i < hi; ++i) s += g[i];
  sh[t] = s;
  __syncthreads();
  for (int d = 1; d < 256; d <<= 1) {
    int v = (t >= d) ? sh[t - d] : 0;
    __syncthreads();
    sh[t] += v;
    __syncthreads();
  }
  int run = sh[t] - s;
  for (int i = lo; i < hi; ++i) { int v = g[i]; g[i] = run; run += v; }
}

// scatter: block b's writes to bucket k form one contiguous run (write-amp ~1x)
// pack.x = col | (row%BKW)<<16 ; pack.y = fixed16(val) in [0,65535]
__global__ __launch_bounds__(256) void part_scatter(
    const int* __restrict__ r1, const int* __restrict__ c1, const float* __restrict__ v1, int e1,
    const int* __restrict__ r2, const int* __restrict__ c2, const float* __restrict__ v2, int e2,
    const int* __restrict__ g1, const int* __restrict__ g2,
    int2* __restrict__ pack1, int2* __restrict__ pack2, int nbk) {
  const int m = blockIdx.y;
  const int NB = m ? NB2 : NB1;
  const int b = blockIdx.x;
  if (b >= NB) return;
  const int* rows = m ? r2 : r1;
  const int* cols = m ? c2 : c1;
  const float* vals = m ? v2 : v1;
  const int E = m ? e2 : e1;
  const int* g = m ? g2 : g1;
  int2* pack = m ? pack2 : pack1;
  __shared__ int lcur[512];
  for (int k = threadIdx.x; k < nbk; k += 256) lcur[k] = g[(size_t)k * NB + b];
  __syncthreads();
  const int ch = (E + NB - 1) / NB;
  const int lo = b * ch, hi = min(lo + ch, E);
  for (int i = lo + threadIdx.x; i < hi; i += 256) {
    int r = rows[i];
    int pos = atomicAdd(&lcur[r >> BKLG], 1);
    unsigned u = (unsigned)(vals[i] * 65536.0f);
    if (u > 65535u) u = 65535u;
    pack[pos] = make_int2(cols[i] | ((r & (BKW - 1)) << 16), (int)u);
  }
}

// per-bucket LDS counting sort (256 rows) -> row-sorted 4B edges + per-row rp
__global__ __launch_bounds__(256) void bucket_sort(
    const int2* __restrict__ pack1, const int* __restrict__ g1,
    unsigned* __restrict__ srt1, int* __restrict__ rp1, int e1,
    const int2* __restrict__ pack2, const int* __restrict__ g2,
    unsigned* __restrict__ srt2, int* __restrict__ rp2, int e2,
    int n, int nbk) {
  const int m = blockIdx.y;
  const int NB = m ? NB2 : NB1;
  const int2* pack = m ? pack2 : pack1;
  const int* g = m ? g2 : g1;
  unsigned* srt = m ? srt2 : srt1;
  int* rp = m ? rp2 : rp1;
  const int E = m ? e2 : e1;
  const int k = blockIdx.x;
  const int base = g[(size_t)k * NB];
  const int end = (k + 1 < nbk) ? g[(size_t)(k + 1) * NB] : E;
  __shared__ int lcnt[256], lws[256], lcur[256];
  const int t = threadIdx.x;
  lcnt[t] = 0;
  __syncthreads();
  for (int i = base + t; i < end; i += 256)
    atomicAdd(&lcnt[(pack[i].x >> 16) & (BKW - 1)], 1);
  __syncthreads();
  int s = lcnt[t];
  lws[t] = s;
  __syncthreads();
  for (int d = 1; d < 256; d <<= 1) {
    int v = (t >= d) ? lws[t - d] : 0;
    __syncthreads();
    lws[t] += v;
    __syncthreads();
  }
  int excl = base + lws[t] - s;
  lcur[t] = excl;
  int row = k * BKW + t;
  if (row < n) rp[row] = excl;
  if (k == nbk - 1 && t == 0) rp[n] = E;
  __syncthreads();
  for (int i = base + t; i < end; i += 256) {
    int2 e = pack[i];
    int pos = atomicAdd(&lcur[(e.x >> 16) & (BKW - 1)], 1);
    srt[pos] = (unsigned)(e.x & 0xFFFF) | ((unsigned)e.y << 16);
  }
}

__device__ __forceinline__ float dec_val(unsigned e) {
  return ((float)(e >> 16) + 0.5f) * (1.0f / 65536.0f);
}

// ---------------- fused SpMM (both matrices, 48-wide) + combine ----------------
// wsum = s0 + A1@p1 + A2@p2 ; m3 = A1@q3a + A2@q3b ; m4 = A1@q4a + A2@q4b
__global__ __launch_bounds__(256) void spmm48_both(
    const unsigned* __restrict__ srt1, const int* __restrict__ rp1,
    const unsigned* __restrict__ srt2, const int* __restrict__ rp2,
    const __half* __restrict__ Pa1, const __half* __restrict__ Pa2,
    const float* __restrict__ s0f, float* __restrict__ wsum,
    float* __restrict__ m3, float* __restrict__ m4, int n) {
  const int row = blockIdx.x * 4 + (threadIdx.x >> 6);
  if (row >= n) return;
  const int lane = threadIdx.x & 63;
  const int c = lane & 15, g = lane >> 4;
  float a0 = 0.f, a1 = 0.f, a2 = 0.f, b0 = 0.f, b1 = 0.f, b2 = 0.f;
  int j1 = rp1[row + 1];
  for (int j = rp1[row] + g; j < j1; j += 4) {
    unsigned e = srt1[j];
    float v = dec_val(e);
    float2 raw = *(const float2*)(Pa1 + ((size_t)(e & 0xFFFF) * 16 + c) * 4);
    float2 f0 = __half22float2(*(__half2*)&raw.x);
    float2 f1 = __half22float2(*(__half2*)&raw.y);
    a0 += v * f0.x; a1 += v * f0.y; a2 += v * f1.x;
  }
  j1 = rp2[row + 1];
  for (int j = rp2[row] + g; j < j1; j += 4) {
    unsigned e = srt2[j];
    float v = dec_val(e);
    float2 raw = *(const float2*)(Pa2 + ((size_t)(e & 0xFFFF) * 16 + c) * 4);
    float2 f0 = __half22float2(*(__half2*)&raw.x);
    float2 f1 = __half22float2(*(__half2*)&raw.y);
    b0 += v * f0.x; b1 += v * f0.y; b2 += v * f1.x;
  }
  a0 += __shfl_xor(a0, 16); a0 += __shfl_xor(a0, 32);
  a1 += __shfl_xor(a1, 16); a1 += __shfl_xor(a1, 32);
  a2 += __shfl_xor(a2, 16); a2 += __shfl_xor(a2, 32);
  b0 += __shfl_xor(b0, 16); b0 += __shfl_xor(b0, 32);
  b1 += __shfl_xor(b1, 16); b1 += __shfl_xor(b1, 32);
  b2 += __shfl_xor(b2, 16); b2 += __shfl_xor(b2, 32);
  if (g == 0) {
    size_t ro = (size_t)row * 16 + c;
    wsum[ro] = s0f[ro] + a0 + b0;
    m3[ro] = a1 + b1;
    m4[ro] = a2 + b2;
  }
}

// ---------------- final: logits = wsum + A1@m3 + A2@m4; softmax ----------------
__global__ __launch_bounds__(256) void final_spmm_softmax(
    const unsigned* __restrict__ srt1, const int* __restrict__ rp1,
    const unsigned* __restrict__ srt2, const int* __restrict__ rp2,
    const float* __restrict__ wsum, const float* __restrict__ m3,
    const float* __restrict__ m4, float* __restrict__ out, int n) {
  const int row = blockIdx.x * 4 + (threadIdx.x >> 6);
  if (row >= n) return;
  const int lane = threadIdx.x & 63;
  const int c = lane & 15, g = lane >> 4;
  float accA = 0.f, accB = 0.f;
  int j1 = rp1[row + 1];
  for (int j = rp1[row] + g; j < j1; j += 4) {
    unsigned e = srt1[j];
    accA += dec_val(e) * m3[(size_t)(e & 0xFFFF) * 16 + c];
  }
  j1 = rp2[row + 1];
  for (int j = rp2[row] + g; j < j1; j += 4) {
    unsigned e = srt2[j];
    accB += dec_val(e) * m4[(size_t)(e & 0xFFFF) * 16 + c];
  }
  accA += __shfl_xor(accA, 16); accA += __shfl_xor(accA, 32);
  accB += __shfl_xor(accB, 16); accB += __shfl_xor(accB, 32);
  float logit = wsum[(size_t)row * 16 + c] + accA + accB;
  float m = logit;
#pragma unroll
  for (int off = 1; off < 16; off <<= 1) m = fmaxf(m, __shfl_xor(m, off));
  float e = __expf(logit - m);
  float s = e;
#pragma unroll
  for (int off = 1; off < 16; off <<= 1) s += __shfl_xor(s, off);
  float p = e / s;
  if (lane < 16) out[(size_t)row * NCLS + lane] = p;
}

extern "C" void kernel_launch(void* const* d_in, const int* in_sizes, int n_in,
                              void* d_out, int out_size, void* d_ws, size_t ws_size,
                              hipStream_t stream) {
  const float* x   = (const float*)d_in[0];
  const int*   a1r = (const int*)d_in[1];
  const int*   a1c = (const int*)d_in[2];
  const float* a1v = (const float*)d_in[3];
  const int*   a2r = (const int*)d_in[4];
  const int*   a2c = (const int*)d_in[5];
  const float* a2v = (const float*)d_in[6];
  const float* we  = (const float*)d_in[7];
  const float* wc  = (const float*)d_in[8];
  const int n  = in_sizes[0] / INF;   // 50000 (<= 65536 for 16-bit col pack)
  const int e1 = in_sizes[1];         // 1,000,000
  const int e2 = in_sizes[4];         // 1,500,000
  const int nbk = (n + BKW - 1) >> BKLG;   // 196 buckets of 256 rows

  // ---- workspace layout (~83 MB) ----
  char* w = (char*)d_ws;
  size_t off = 0;
  unsigned short* r0h = (unsigned short*)(w + off); off += (size_t)n * HID * 2;     // 12.8 MB
  unsigned short* r0l = (unsigned short*)(w + off); off += (size_t)n * HID * 2;     // 12.8 MB
  float* s0f  = (float*)(w + off); off += (size_t)n * 16 * 4;                       //  3.2 MB
  __half* Pa1 = (__half*)(w + off); off += (size_t)n * 64 * 2;                      //  6.4 MB
  __half* Pa2 = (__half*)(w + off); off += (size_t)n * 64 * 2;                      //  6.4 MB
  float* wsum = (float*)(w + off); off += (size_t)n * 16 * 4;                       //  3.2 MB
  float* m3   = (float*)(w + off); off += (size_t)n * 16 * 4;                       //  3.2 MB
  float* m4   = (float*)(w + off); off += (size_t)n * 16 * 4;                       //  3.2 MB
  int2* pack1 = (int2*)(w + off);  off += (size_t)e1 * 8;                           //  8 MB
  int2* pack2 = (int2*)(w + off);  off += (size_t)e2 * 8;                           // 12 MB
  unsigned* srt1 = (unsigned*)(w + off); off += (size_t)e1 * 4;                     //  4 MB
  unsigned* srt2 = (unsigned*)(w + off); off += (size_t)e2 * 4;                     //  6 MB
  unsigned short* wefh = (unsigned short*)(w + off); off += (size_t)512 * HID * 2;  // 128 KB
  unsigned short* wefl = (unsigned short*)(w + off); off += (size_t)512 * HID * 2;  // 128 KB
  unsigned short* wcfh = (unsigned short*)(w + off); off += (size_t)HID * PW * 2;   //  28 KB
  unsigned short* wcfl = (unsigned short*)(w + off); off += (size_t)HID * PW * 2;   //  28 KB
  int* g1 = (int*)(w + off); off += (size_t)512 * NB1 * 4;                          // 256 KB
  int* g2 = (int*)(w + off); off += (size_t)512 * NB2 * 4;                          // 384 KB
  int* rp1 = (int*)(w + off); off += (size_t)(n + 1) * 4;
  int* rp2 = (int*)(w + off); off += (size_t)(n + 1) * 4;

  prep_w<<<312, 256, 0, stream>>>(we, wc, wefh, wefl, wcfh, wcfl);
  embed_mfma<<<(n + 63) / 64, 256, 0, stream>>>(x, wefh, wefl, r0h, r0l, n);
  proj_mfma<<<(n + 63) / 64, 256, 0, stream>>>(r0h, r0l, wcfh, wcfl, s0f, Pa1, Pa2, n);

  part_hist<<<dim3(NB2, 2), 256, 0, stream>>>(a1r, e1, a2r, e2, g1, g2, nbk);
  part_scan<<<2, 256, 0, stream>>>(g1, nbk * NB1, g2, nbk * NB2);
  part_scatter<<<dim3(NB2, 2), 256, 0, stream>>>(
      a1r, a1c, a1v, e1, a2r, a2c, a2v, e2, g1, g2, pack1, pack2, nbk);
  bucket_sort<<<dim3(nbk, 2), 256, 0, stream>>>(
      pack1, g1, srt1, rp1, e1, pack2, g2, srt2, rp2, e2, n, nbk);

  spmm48_both<<<(n + 3) / 4, 256, 0, stream>>>(
      srt1, rp1, srt2, rp2, Pa1, Pa2, s0f, wsum, m3, m4, n);
  final_spmm_softmax<<<(n + 3) / 4, 256, 0, stream>>>(
      srt1, rp1, srt2, rp2, wsum, m3, m4, (float*)d_out, n);
}